// Round 1
// baseline (84.270 us; speedup 1.0000x reference)
//
#include <hip/hip_runtime.h>
#include <math.h>

#define BB 16
#define SS 2048
#define HH 2
#define ROWS_PER_BLOCK 128
#define THREADS1 256          // 4 waves; each wave owns TWO 16-row tiles (32 rows)
#define KT 16                 // keys per inner iteration
#define NITER (SS / KT)       // 128
#define KVT_STRIDE 2064       // 4128B row stride == +8 banks (conflict-free, verified)

typedef _Float16 half8 __attribute__((ext_vector_type(8)));
typedef _Float16 half4h __attribute__((ext_vector_type(4)));
typedef _Float16 half2h __attribute__((ext_vector_type(2)));
typedef float floatx4 __attribute__((ext_vector_type(4)));

__device__ __forceinline__ float fast_exp2(float x) {
  return __builtin_amdgcn_exp2f(x);
}

__device__ __forceinline__ half2h pkrtz(float a, float b) {
#if defined(__has_builtin)
#if __has_builtin(__builtin_amdgcn_cvt_pkrtz)
  return __builtin_bit_cast(half2h, __builtin_amdgcn_cvt_pkrtz(a, b));
#else
  half2h r; r[0] = (_Float16)a; r[1] = (_Float16)b; return r;
#endif
#else
  half2h r; r[0] = (_Float16)a; r[1] = (_Float16)b; return r;
#endif
}

// One fused kernel. grid: [b(16)][h(2)][rb(16)] = 512 blocks -> 2 blocks/CU.
// Block: stage kv = cos(x+theta) (f16, half4 now - no stored zeros) for all
// 2048 keys of its head; 4 waves, wave wv sweeps rows [rb*128+wv*32, +32):
// per iteration ONE ds_read_b64 key tile + ONE ds_read_b64 kvT tile feed
// TWO QK MFMAs and TWO PV MFMAs (LDS traffic per row-tile cut 3x vs the
// previous 16-rows/wave half8 version). exp on VALU; PV via MFMA with a
// ones-column giving the softmax denominator.
// Epilogue: normalize + 8x8 out-projection in-block, atomicAdd per head.
__global__ __launch_bounds__(THREADS1, 2)
void qattn_fused(const float* __restrict__ x,
                 const float* __restrict__ theta,
                 const float* __restrict__ w_out,
                 const float* __restrict__ b_out,
                 float* __restrict__ out) {
  __shared__ half4h s_keys[SS];              // [key][4] f16 (16 KB)
  __shared__ _Float16 s_kvT[5 * KVT_STRIDE]; // rows 0-3 = kv^T, row 4 = ones (20.2 KB)
  __shared__ float po[ROWS_PER_BLOCK * 6];   // epilogue: per-row o[4],l (3 KB)

  const int bid = blockIdx.x;
  const int rb  = bid & 15;
  const int h   = (bid >> 4) & 1;
  const int b   = bid >> 5;
  const int t   = threadIdx.x;

  const float4 th = ((const float4*)theta)[h];
  const float4* xb = (const float4*)x;       // element (b*SS+s)*2 + h

  // --- stage cos(x+theta) as f16: key rows (half4) and kv^T + ones ---
  for (int s = t; s < SS; s += THREADS1) {
    float4 xr = xb[(size_t)(b * SS + s) * 2 + h];
    _Float16 c0 = (_Float16)__cosf(xr.x + th.x);
    _Float16 c1 = (_Float16)__cosf(xr.y + th.y);
    _Float16 c2 = (_Float16)__cosf(xr.z + th.z);
    _Float16 c3 = (_Float16)__cosf(xr.w + th.w);
    half4h v = {c0, c1, c2, c3};
    s_keys[s] = v;
    s_kvT[0 * KVT_STRIDE + s] = c0;
    s_kvT[1 * KVT_STRIDE + s] = c1;
    s_kvT[2 * KVT_STRIDE + s] = c2;
    s_kvT[3 * KVT_STRIDE + s] = c3;
  }
  for (int i = t; i < KVT_STRIDE; i += THREADS1)
    s_kvT[4 * KVT_STRIDE + i] = (_Float16)1.0f;   // ones column -> denominator
  __syncthreads();

  const int lane = t & 63;
  const int wv   = t >> 6;        // wave id 0..3 -> 32-row tile
  const int quad = lane >> 4;
  const int l15  = lane & 15;

  // QK B-operands (this wave's two 16-row query tiles, scaled by 0.5*log2e).
  // B[k=j][n=l15] nonzero only for quad==0, j<4.
  const float KS  = 0.72134752044448170367f;   // 0.5 * log2(e)
  const float scl = (lane < 16) ? KS : 0.0f;
  const int   qrow = rb * ROWS_PER_BLOCK + wv * 32 + l15;
  half4h rq0 = s_keys[qrow];
  half4h rq1 = s_keys[qrow + 16];
  const _Float16 z = (_Float16)0.0f;
  half8 bq0 = {(_Float16)((float)rq0[0] * scl), (_Float16)((float)rq0[1] * scl),
               (_Float16)((float)rq0[2] * scl), (_Float16)((float)rq0[3] * scl),
               z, z, z, z};
  half8 bq1 = {(_Float16)((float)rq1[0] * scl), (_Float16)((float)rq1[1] * scl),
               (_Float16)((float)rq1[2] * scl), (_Float16)((float)rq1[3] * scl),
               z, z, z, z};

  // PV B-operand: B[k=8q+j][n=l15] = kvT[min(l15,4)][kt*16 + 4q + j], j<4
  const _Float16* bbase = s_kvT + (l15 < 4 ? l15 : 4) * KVT_STRIDE + quad * 4;

  floatx4 o0 = {0.f, 0.f, 0.f, 0.f};
  floatx4 o1 = {0.f, 0.f, 0.f, 0.f};
  const floatx4 zf = {0.f, 0.f, 0.f, 0.f};
  half8 apv0 = {z, z, z, z, z, z, z, z};
  half8 apv1 = {z, z, z, z, z, z, z, z};

#pragma unroll 4
  for (int kt = 0; kt < NITER; ++kt) {
    // QK A-operand: A[m=l15][k=8q+j] = key (kt*16+l15), j<4 real, rest zero.
    // One b64 read + one b64 read feed BOTH row-tiles.
    half4h al = s_keys[kt * KT + l15];
    half8 a = {al[0], al[1], al[2], al[3], z, z, z, z};
    half4h bl = *(const half4h*)(bbase + kt * KT);
    half8 bpv = {bl[0], bl[1], bl[2], bl[3], z, z, z, z};

    // scores C[key=4q+reg][row=l15], pre-scaled for exp2
    floatx4 c0 = __builtin_amdgcn_mfma_f32_16x16x32_f16(a, bq0, zf, 0, 0, 0);
    floatx4 c1 = __builtin_amdgcn_mfma_f32_16x16x32_f16(a, bq1, zf, 0, 0, 0);

    // P tiles directly in PV A-operand layout: A[m=l15][k=8q+j] = P[row][key 4q+j]
    half2h p01 = pkrtz(fast_exp2(c0[0]), fast_exp2(c0[1]));
    half2h p23 = pkrtz(fast_exp2(c0[2]), fast_exp2(c0[3]));
    apv0[0] = p01[0]; apv0[1] = p01[1]; apv0[2] = p23[0]; apv0[3] = p23[1];
    half2h p45 = pkrtz(fast_exp2(c1[0]), fast_exp2(c1[1]));
    half2h p67 = pkrtz(fast_exp2(c1[2]), fast_exp2(c1[3]));
    apv1[0] = p45[0]; apv1[1] = p45[1]; apv1[2] = p67[0]; apv1[3] = p67[1];

    o0 = __builtin_amdgcn_mfma_f32_16x16x32_f16(apv0, bpv, o0, 0, 0, 0);
    o1 = __builtin_amdgcn_mfma_f32_16x16x32_f16(apv1, bpv, o1, 0, 0, 0);
  }

  // O/D layout: col n=l15 (0-3 = numerator wires, 4 = l), row m = quad*4+reg
  if (l15 < 5) {
#pragma unroll
    for (int r = 0; r < 4; ++r) {
      const int base = wv * 32 + quad * 4 + r;
      po[base * 6 + l15]        = o0[r];
      po[(base + 16) * 6 + l15] = o1[r];
    }
  }
  __syncthreads();

  // --- normalize + out-projection; atomicAdd merges the two heads ---
  {
    const int row = t >> 1;           // 0..127
    const int ep  = (t & 1) * 4;      // output cols {ep .. ep+3}
    const float* pr = po + row * 6;
    const float inv = 1.0f / pr[4];
    const float o0v = pr[0] * inv, o1v = pr[1] * inv,
                o2v = pr[2] * inv, o3v = pr[3] * inv;
    float* op = out + ((size_t)(b * SS + rb * ROWS_PER_BLOCK + row)) * 8;
#pragma unroll
    for (int k = 0; k < 4; ++k) {
      const int e = ep + k;
      const float* wr = w_out + e * 8 + h * 4;
      float val = fmaf(o0v, wr[0], fmaf(o1v, wr[1], fmaf(o2v, wr[2], o3v * wr[3])));
      if (h == 0) val += b_out[e];
      atomicAdd(op + e, val);
    }
  }
}

extern "C" void kernel_launch(void* const* d_in, const int* in_sizes, int n_in,
                              void* d_out, int out_size, void* d_ws, size_t ws_size,
                              hipStream_t stream) {
  const float* x     = (const float*)d_in[0];
  const float* theta = (const float*)d_in[1];
  const float* w_out = (const float*)d_in[2];
  const float* b_out = (const float*)d_in[3];
  float* out = (float*)d_out;
  (void)in_sizes; (void)n_in; (void)d_ws; (void)ws_size;

  // two head-blocks accumulate into each output cell: zero first
  (void)hipMemsetAsync(d_out, 0, (size_t)out_size * sizeof(float), stream);
  qattn_fused<<<dim3(BB * HH * 16), THREADS1, 0, stream>>>(x, theta, w_out, b_out, out);
}

// Round 2
// 83.746 us; speedup vs baseline: 1.0063x; 1.0063x over previous
//
#include <hip/hip_runtime.h>
#include <math.h>

#define BB 16
#define SS 2048
#define HH 2
#define ROWS_PER_BLOCK 128
#define THREADS1 512          // 8 waves; wave owns one 16-row tile (R0 structure)
#define KT 16                 // keys per inner iteration
#define NITER (SS / KT)       // 128
#define KVT_STRIDE 2064       // 4128B row stride == +8 banks (conflict-free, verified)

typedef _Float16 half8 __attribute__((ext_vector_type(8)));
typedef _Float16 half4h __attribute__((ext_vector_type(4)));
typedef _Float16 half2h __attribute__((ext_vector_type(2)));
typedef float floatx4 __attribute__((ext_vector_type(4)));

__device__ __forceinline__ float fast_exp2(float x) {
  return __builtin_amdgcn_exp2f(x);
}

__device__ __forceinline__ half2h pkrtz(float a, float b) {
#if defined(__has_builtin)
#if __has_builtin(__builtin_amdgcn_cvt_pkrtz)
  return __builtin_bit_cast(half2h, __builtin_amdgcn_cvt_pkrtz(a, b));
#else
  half2h r; r[0] = (_Float16)a; r[1] = (_Float16)b; return r;
#endif
#else
  half2h r; r[0] = (_Float16)a; r[1] = (_Float16)b; return r;
#endif
}

// One fused kernel. grid: [b(16)][h(2)][rb(16)] = 512 blocks -> 2 blocks/CU.
// Block: stage kv = cos(x+theta) (f16, half4 - no stored zeros) for all 2048
// keys of its head; 8 waves (4/SIMD for staging latency-hiding), wave wv
// sweeps rows [rb*128+wv*16, +16) x all keys: QK via MFMA (ds_read_b64
// A-tile, hi-half zeros live in registers), exp on VALU, PV via MFMA with a
// ones-column giving the softmax denominator.
// Epilogue: normalize + 8x8 out-projection in-block, atomicAdd per head.
__global__ __launch_bounds__(THREADS1, 4)
void qattn_fused(const float* __restrict__ x,
                 const float* __restrict__ theta,
                 const float* __restrict__ w_out,
                 const float* __restrict__ b_out,
                 float* __restrict__ out) {
  __shared__ half4h s_keys[SS];              // [key][4] f16 (16 KB)
  __shared__ _Float16 s_kvT[5 * KVT_STRIDE]; // rows 0-3 = kv^T, row 4 = ones (20.2 KB)
  __shared__ float po[ROWS_PER_BLOCK * 6];   // epilogue: per-row o[4],l (3 KB)

  const int bid = blockIdx.x;
  const int rb  = bid & 15;
  const int h   = (bid >> 4) & 1;
  const int b   = bid >> 5;
  const int t   = threadIdx.x;

  const float4 th = ((const float4*)theta)[h];
  const float4* xb = (const float4*)x;       // element (b*SS+s)*2 + h

  // --- stage cos(x+theta) as f16: key rows (half4) and kv^T + ones ---
  for (int s = t; s < SS; s += THREADS1) {
    float4 xr = xb[(size_t)(b * SS + s) * 2 + h];
    _Float16 c0 = (_Float16)__cosf(xr.x + th.x);
    _Float16 c1 = (_Float16)__cosf(xr.y + th.y);
    _Float16 c2 = (_Float16)__cosf(xr.z + th.z);
    _Float16 c3 = (_Float16)__cosf(xr.w + th.w);
    half4h v = {c0, c1, c2, c3};
    s_keys[s] = v;
    s_kvT[0 * KVT_STRIDE + s] = c0;
    s_kvT[1 * KVT_STRIDE + s] = c1;
    s_kvT[2 * KVT_STRIDE + s] = c2;
    s_kvT[3 * KVT_STRIDE + s] = c3;
  }
  for (int i = t; i < KVT_STRIDE; i += THREADS1)
    s_kvT[4 * KVT_STRIDE + i] = (_Float16)1.0f;   // ones column -> denominator
  __syncthreads();

  const int lane = t & 63;
  const int wv   = t >> 6;        // wave id 0..7 -> 16-row tile
  const int quad = lane >> 4;
  const int l15  = lane & 15;

  // QK B-operand (this wave's 16 query rows, scaled by 0.5*log2e), built once.
  // B[k=j][n=l15] nonzero only for quad==0, j<4.
  const float KS  = 0.72134752044448170367f;   // 0.5 * log2(e)
  const float scl = (lane < 16) ? KS : 0.0f;
  const int   qrow = rb * ROWS_PER_BLOCK + wv * 16 + l15;
  half4h rq = s_keys[qrow];
  const _Float16 z = (_Float16)0.0f;
  half8 bq = {(_Float16)((float)rq[0] * scl), (_Float16)((float)rq[1] * scl),
              (_Float16)((float)rq[2] * scl), (_Float16)((float)rq[3] * scl),
              z, z, z, z};

  // PV B-operand: B[k=8q+j][n=l15] = kvT[min(l15,4)][kt*16 + 4q + j], j<4
  const _Float16* bbase = s_kvT + (l15 < 4 ? l15 : 4) * KVT_STRIDE + quad * 4;

  floatx4 o = {0.f, 0.f, 0.f, 0.f};
  const floatx4 zf = {0.f, 0.f, 0.f, 0.f};
  half8 apv = {z, z, z, z, z, z, z, z};

#pragma unroll 4
  for (int kt = 0; kt < NITER; ++kt) {
    // QK A-operand: A[m=l15][k=8q+j] = key (kt*16+l15), j<4 real, hi zeros
    // stay in fixed registers (ds_read_b64, not b128).
    half4h al = s_keys[kt * KT + l15];
    half8 a = {al[0], al[1], al[2], al[3], z, z, z, z};
    half4h bl = *(const half4h*)(bbase + kt * KT);
    half8 bpv = {bl[0], bl[1], bl[2], bl[3], z, z, z, z};

    // scores C[key=4q+reg][row=l15], pre-scaled for exp2
    floatx4 c = __builtin_amdgcn_mfma_f32_16x16x32_f16(a, bq, zf, 0, 0, 0);

    // P tile directly in PV A-operand layout: A[m=l15][k=8q+j] = P[row][key 4q+j]
    half2h p01 = pkrtz(fast_exp2(c[0]), fast_exp2(c[1]));
    half2h p23 = pkrtz(fast_exp2(c[2]), fast_exp2(c[3]));
    apv[0] = p01[0]; apv[1] = p01[1]; apv[2] = p23[0]; apv[3] = p23[1];

    o = __builtin_amdgcn_mfma_f32_16x16x32_f16(apv, bpv, o, 0, 0, 0);
  }

  // O/D layout: col n=l15 (0-3 = numerator wires, 4 = l), row m = quad*4+reg
  if (l15 < 5) {
#pragma unroll
    for (int r = 0; r < 4; ++r)
      po[(wv * 16 + quad * 4 + r) * 6 + l15] = o[r];
  }
  __syncthreads();

  // --- normalize + out-projection; atomicAdd merges the two heads ---
  {
    const int row = t >> 2;           // 0..127
    const int ep  = (t & 3) * 2;      // output cols {ep, ep+1}
    const float* pr = po + row * 6;
    const float inv = 1.0f / pr[4];
    const float o0 = pr[0] * inv, o1 = pr[1] * inv,
                o2 = pr[2] * inv, o3 = pr[3] * inv;
    float* op = out + ((size_t)(b * SS + rb * ROWS_PER_BLOCK + row)) * 8;
#pragma unroll
    for (int k = 0; k < 2; ++k) {
      const int e = ep + k;
      const float* wr = w_out + e * 8 + h * 4;
      float val = fmaf(o0, wr[0], fmaf(o1, wr[1], fmaf(o2, wr[2], o3 * wr[3])));
      if (h == 0) val += b_out[e];
      atomicAdd(op + e, val);
    }
  }
}

extern "C" void kernel_launch(void* const* d_in, const int* in_sizes, int n_in,
                              void* d_out, int out_size, void* d_ws, size_t ws_size,
                              hipStream_t stream) {
  const float* x     = (const float*)d_in[0];
  const float* theta = (const float*)d_in[1];
  const float* w_out = (const float*)d_in[2];
  const float* b_out = (const float*)d_in[3];
  float* out = (float*)d_out;
  (void)in_sizes; (void)n_in; (void)d_ws; (void)ws_size;

  // two head-blocks accumulate into each output cell: zero first
  (void)hipMemsetAsync(d_out, 0, (size_t)out_size * sizeof(float), stream);
  qattn_fused<<<dim3(BB * HH * 16), THREADS1, 0, stream>>>(x, theta, w_out, b_out, out);
}